// Round 2
// baseline (405.035 us; speedup 1.0000x reference)
//
#include <hip/hip_runtime.h>
#include <stdint.h>

#define B_ 16
#define C_ 512
#define N_ 4096

typedef float f32x4 __attribute__((ext_vector_type(4)));
typedef __bf16 bf16x8 __attribute__((ext_vector_type(8)));

// fp32 -> bf16 round-to-nearest-even (inputs are finite normals; no NaN path needed)
static __device__ __forceinline__ unsigned short f2bf(float f) {
    unsigned int u = __float_as_uint(f);
    u += 0x7fffu + ((u >> 16) & 1u);
    return (unsigned short)(u >> 16);
}

// async global->LDS, 16B per lane (global_load_lds_dwordx4)
static __device__ __forceinline__ void gload_lds16(const void* g, void* l) {
    __builtin_amdgcn_global_load_lds(
        (__attribute__((address_space(1))) unsigned int*)(g),
        (__attribute__((address_space(3))) unsigned int*)(l),
        16, 0, 0);
}

// Cooperative stage of one 128x32 A-tile and 128x32 B-tile into LDS.
// 4 global_load_lds_dwordx4 per wave per call => vmcnt +4.
static __device__ __forceinline__ void stage_pair(const char* Ab, const char* Bb,
                                                  char* as, char* bs, int tid,
                                                  int rowBytes, int m0, int n0, int kByte) {
#pragma unroll
    for (int i = 0; i < 2; ++i) {
        int o = (i * 256 + tid) * 16;            // LDS byte offset, 0..8191
        int mrow = o >> 6, inrow = o & 63;       // 64 B per 32-elem bf16 row
        gload_lds16(Ab + (size_t)(m0 + mrow) * rowBytes + kByte + inrow, as + o);
        gload_lds16(Bb + (size_t)(n0 + mrow) * rowBytes + kByte + inrow, bs + o);
    }
}

// ---------------------------------------------------------------------------
// Kernel 1: x (fp32, BxCxN) -> q16 (bf16, BxCxN) and qt16 (bf16, BxNxC)
// Register 4x4 micro-tile transpose: no LDS, no barriers.
// ---------------------------------------------------------------------------
__global__ __launch_bounds__(256)
void convert_transpose(const float* __restrict__ x,
                       unsigned short* __restrict__ q16,
                       unsigned short* __restrict__ qt16) {
    int b = blockIdx.z;
    int t = threadIdx.x;
    int c0 = blockIdx.y * 64 + (t >> 4) * 4;
    int n0 = blockIdx.x * 64 + (t & 15) * 4;

    const float* xb = x + ((size_t)b * C_ + c0) * N_ + n0;
    unsigned short h[4][4];
#pragma unroll
    for (int i = 0; i < 4; ++i) {
        float4 v = *(const float4*)(xb + (size_t)i * N_);
        h[i][0] = f2bf(v.x); h[i][1] = f2bf(v.y);
        h[i][2] = f2bf(v.z); h[i][3] = f2bf(v.w);
    }
    unsigned short* qb = q16 + ((size_t)b * C_ + c0) * N_ + n0;
#pragma unroll
    for (int i = 0; i < 4; ++i) {
        ushort4 p; p.x = h[i][0]; p.y = h[i][1]; p.z = h[i][2]; p.w = h[i][3];
        *(ushort4*)(qb + (size_t)i * N_) = p;
    }
    unsigned short* qtb = qt16 + ((size_t)b * N_ + n0) * C_ + c0;
#pragma unroll
    for (int j = 0; j < 4; ++j) {
        ushort4 p; p.x = h[0][j]; p.y = h[1][j]; p.z = h[2][j]; p.w = h[3][j];
        *(ushort4*)(qtb + (size_t)j * C_) = p;
    }
}

// ---------------------------------------------------------------------------
// Kernel 2: energy upper-triangle partials, split-K x4.
//   part[ks][b] (f32, 512x512) = Q[b][:, ks*1024:(ks+1)*1024] . (same)^T,
//   computed only for 128x128 tiles with m_tile <= n_tile (Gram symmetry).
// Depth-3 counted-vmcnt pipeline: 4 LDS buffers, stage tile t+3, wait
// vmcnt(8) steady state. 640 blocks, XCD-swizzled.
// ---------------------------------------------------------------------------
__global__ __launch_bounds__(256)
void gemm_energy_upper(const unsigned short* __restrict__ q16,
                       float* __restrict__ part) {
    // linearize + XCD-aware swizzle (640 = 8 * 80)
    int p = (blockIdx.z * 4 + blockIdx.y) * 10 + blockIdx.x;
    int l = (p & 7) * 80 + (p >> 3);
    int tile = l % 10;
    int ks   = (l / 10) & 3;
    int b    = l / 40;

    int my, nx;
    if (tile < 4)      { my = 0; nx = tile; }
    else if (tile < 7) { my = 1; nx = tile - 3; }
    else if (tile < 9) { my = 2; nx = tile - 5; }
    else               { my = 3; nx = 3; }
    int m0 = my * 128, n0 = nx * 128;
    int kbeg = ks * 1024;
    const int NT = 32;                       // 1024 / 32

    const char* Ab = (const char*)(q16 + (size_t)b * C_ * N_);
    const int rowB = N_ * 2;

    __shared__ unsigned short As[4][128 * 32];
    __shared__ unsigned short Bs[4][128 * 32];

    int t = threadIdx.x;
    int lane = t & 63, wave = t >> 6;
    int wm = (wave >> 1) * 64, wn = (wave & 1) * 64;
    int qd = lane >> 4, r = lane & 15;

    f32x4 acc[4][4] = {};

    stage_pair(Ab, Ab, (char*)As[0], (char*)Bs[0], t, rowB, m0, n0, (kbeg +  0) * 2);
    stage_pair(Ab, Ab, (char*)As[1], (char*)Bs[1], t, rowB, m0, n0, (kbeg + 32) * 2);
    stage_pair(Ab, Ab, (char*)As[2], (char*)Bs[2], t, rowB, m0, n0, (kbeg + 64) * 2);

    for (int tt = 0; tt < NT; ++tt) {
        if (tt < NT - 2)       asm volatile("s_waitcnt vmcnt(8) lgkmcnt(0)" ::: "memory");
        else if (tt == NT - 2) asm volatile("s_waitcnt vmcnt(4) lgkmcnt(0)" ::: "memory");
        else                   asm volatile("s_waitcnt vmcnt(0) lgkmcnt(0)" ::: "memory");
        __builtin_amdgcn_s_barrier();

        if (tt + 3 < NT) {
            int nb = (tt + 3) & 3;
            stage_pair(Ab, Ab, (char*)As[nb], (char*)Bs[nb], t, rowB,
                       m0, n0, (kbeg + (tt + 3) * 32) * 2);
        }

        const unsigned short* as = As[tt & 3];
        const unsigned short* bs = Bs[tt & 3];
        bf16x8 af[4], bfr[4];
#pragma unroll
        for (int i = 0; i < 4; ++i)
            af[i] = *(const bf16x8*)&as[(wm + i * 16 + r) * 32 + qd * 8];
#pragma unroll
        for (int j = 0; j < 4; ++j)
            bfr[j] = *(const bf16x8*)&bs[(wn + j * 16 + r) * 32 + qd * 8];

        __builtin_amdgcn_s_setprio(1);
#pragma unroll
        for (int i = 0; i < 4; ++i)
#pragma unroll
            for (int j = 0; j < 4; ++j)
                acc[i][j] = __builtin_amdgcn_mfma_f32_16x16x32_bf16(af[i], bfr[j], acc[i][j], 0, 0, 0);
        __builtin_amdgcn_s_setprio(0);
    }

    float* Db = part + ((size_t)ks * B_ + b) * C_ * C_;
#pragma unroll
    for (int i = 0; i < 4; ++i)
#pragma unroll
        for (int j = 0; j < 4; ++j) {
            int row = m0 + wm + i * 16 + qd * 4;
            int col = n0 + wn + j * 16 + r;
#pragma unroll
            for (int rr = 0; rr < 4; ++rr)
                Db[(size_t)(row + rr) * C_ + col] = acc[i][j][rr];
        }
}

// ---------------------------------------------------------------------------
// Kernel 2b: E = sum of 4 partials; mirror upper triangle to lower.
// blockIdx.y 0..5: off-diag 128-tile pairs (m<n); 6..9: diagonal tiles.
// blockIdx.x: 2x2 sub-grid of 64x64 within the 128-tile.
// ---------------------------------------------------------------------------
__global__ __launch_bounds__(256)
void mirror_sum(const float* __restrict__ part, float* __restrict__ E) {
    int b = blockIdx.z, id = blockIdx.y;
    int pm, pn;
    if (id < 3)       { pm = 0; pn = id + 1; }
    else if (id < 5)  { pm = 1; pn = id - 1; }
    else if (id == 5) { pm = 2; pn = 3; }
    else              { pm = id - 6; pn = id - 6; }
    bool diag = (id >= 6);
    int m0 = pm * 128 + (blockIdx.x >> 1) * 64;
    int n0 = pn * 128 + (blockIdx.x & 1) * 64;

    const size_t PS = (size_t)B_ * C_ * C_;
    const float* pb = part + (size_t)b * C_ * C_;
    float*       Eb = E    + (size_t)b * C_ * C_;

    int t = threadIdx.x, tx = t & 15, ty = t >> 4;
    __shared__ float tile[64][68];

#pragma unroll
    for (int s = 0; s < 4; ++s) {
        int rr = s * 16 + ty;
        size_t idx = (size_t)(m0 + rr) * C_ + n0 + tx * 4;
        float4 v0 = *(const float4*)(pb + idx);
        float4 v1 = *(const float4*)(pb + PS + idx);
        float4 v2 = *(const float4*)(pb + 2 * PS + idx);
        float4 v3 = *(const float4*)(pb + 3 * PS + idx);
        float4 v; v.x = v0.x + v1.x + v2.x + v3.x;
                  v.y = v0.y + v1.y + v2.y + v3.y;
                  v.z = v0.z + v1.z + v2.z + v3.z;
                  v.w = v0.w + v1.w + v2.w + v3.w;
        *(float4*)(Eb + idx) = v;
        if (!diag) {
            tile[rr][tx * 4 + 0] = v.x; tile[rr][tx * 4 + 1] = v.y;
            tile[rr][tx * 4 + 2] = v.z; tile[rr][tx * 4 + 3] = v.w;
        }
    }
    if (!diag) {
        __syncthreads();
#pragma unroll
        for (int s = 0; s < 4; ++s) {
            int nr = s * 16 + ty;
            float4 w;
            w.x = tile[tx * 4 + 0][nr];
            w.y = tile[tx * 4 + 1][nr];
            w.z = tile[tx * 4 + 2][nr];
            w.w = tile[tx * 4 + 3][nr];
            *(float4*)(Eb + (size_t)(n0 + nr) * C_ + m0 + tx * 4) = w;
        }
    }
}

// ---------------------------------------------------------------------------
// Kernel 3: attention = softmax(max - energy) = softmax(-energy), row-wise.
// ---------------------------------------------------------------------------
__global__ __launch_bounds__(256)
void softmax_neg(const float* __restrict__ energy, unsigned short* __restrict__ att) {
    size_t row = blockIdx.x;
    const float* e = energy + row * C_;
    int t = threadIdx.x;

    float e0 = e[t], e1 = e[t + 256];
    float m = fminf(e0, e1);                 // min(e) == -max(-e)
#pragma unroll
    for (int off = 32; off > 0; off >>= 1) m = fminf(m, __shfl_down(m, off, 64));
    __shared__ float red[8];
    if ((t & 63) == 0) red[t >> 6] = m;
    __syncthreads();
    m = fminf(fminf(red[0], red[1]), fminf(red[2], red[3]));

    float p0 = __expf(m - e0), p1 = __expf(m - e1);
    float s = p0 + p1;
#pragma unroll
    for (int off = 32; off > 0; off >>= 1) s += __shfl_down(s, off, 64);
    if ((t & 63) == 0) red[4 + (t >> 6)] = s;
    __syncthreads();
    s = red[4] + red[5] + red[6] + red[7];
    float inv = 1.0f / s;

    att[row * C_ + t]       = f2bf(p0 * inv);
    att[row * C_ + t + 256] = f2bf(p1 * inv);
}

// ---------------------------------------------------------------------------
// Kernel 4: y[b] = gamma * (attention[b] . Q[b]) + x[b]
// Depth-3 counted-vmcnt pipeline, 4 LDS buffers, XCD swizzle.
// ---------------------------------------------------------------------------
__global__ __launch_bounds__(256)
void gemm_bt_out(const unsigned short* __restrict__ att,
                 const unsigned short* __restrict__ qt16,
                 const float* __restrict__ x,
                 const float* __restrict__ gamma,
                 float* __restrict__ y) {
    const int K = 512;
    const int NT = K / 32;   // 16
    // linearize + XCD swizzle (2048 = 8 * 256)
    int p = (blockIdx.z * 4 + blockIdx.y) * 32 + blockIdx.x;
    int l = (p & 7) * 256 + (p >> 3);
    int bx = l & 31, by = (l >> 5) & 3, b = l >> 7;

    const char* Ab = (const char*)(att  + (size_t)b * C_ * K);
    const char* Bb = (const char*)(qt16 + (size_t)b * N_ * K);
    int m0 = by * 128;    // c
    int n0 = bx * 128;    // n (spatial)

    __shared__ unsigned short As[4][128 * 32];
    __shared__ unsigned short Bs[4][128 * 32];

    int t = threadIdx.x;
    int lane = t & 63, wave = t >> 6;
    int wm = (wave >> 1) * 64, wn = (wave & 1) * 64;
    int qd = lane >> 4, r = lane & 15;

    f32x4 acc[4][4] = {};

    const int rowB = K * 2;
    stage_pair(Ab, Bb, (char*)As[0], (char*)Bs[0], t, rowB, m0, n0, 0);
    stage_pair(Ab, Bb, (char*)As[1], (char*)Bs[1], t, rowB, m0, n0, 64);
    stage_pair(Ab, Bb, (char*)As[2], (char*)Bs[2], t, rowB, m0, n0, 128);

    for (int tt = 0; tt < NT; ++tt) {
        if (tt < NT - 2)       asm volatile("s_waitcnt vmcnt(8) lgkmcnt(0)" ::: "memory");
        else if (tt == NT - 2) asm volatile("s_waitcnt vmcnt(4) lgkmcnt(0)" ::: "memory");
        else                   asm volatile("s_waitcnt vmcnt(0) lgkmcnt(0)" ::: "memory");
        __builtin_amdgcn_s_barrier();

        if (tt + 3 < NT) {
            int nb = (tt + 3) & 3;
            stage_pair(Ab, Bb, (char*)As[nb], (char*)Bs[nb], t, rowB,
                       m0, n0, (tt + 3) * 64);
        }

        const unsigned short* as = As[tt & 3];
        const unsigned short* bs = Bs[tt & 3];
        bf16x8 af[4], bfr[4];
#pragma unroll
        for (int i = 0; i < 4; ++i)
            af[i] = *(const bf16x8*)&as[(wm + i * 16 + r) * 32 + qd * 8];
#pragma unroll
        for (int j = 0; j < 4; ++j)
            bfr[j] = *(const bf16x8*)&bs[(wn + j * 16 + r) * 32 + qd * 8];

        __builtin_amdgcn_s_setprio(1);
#pragma unroll
        for (int i = 0; i < 4; ++i)
#pragma unroll
            for (int j = 0; j < 4; ++j)
                acc[i][j] = __builtin_amdgcn_mfma_f32_16x16x32_bf16(af[i], bfr[j], acc[i][j], 0, 0, 0);
        __builtin_amdgcn_s_setprio(0);
    }

    float g = gamma[0];
    const float* xb = x + (size_t)b * C_ * N_;
    float*       yb = y + (size_t)b * C_ * N_;
#pragma unroll
    for (int i = 0; i < 4; ++i)
#pragma unroll
        for (int j = 0; j < 4; ++j) {
            int row = m0 + wm + i * 16 + qd * 4;
            int col = n0 + wn + j * 16 + r;
#pragma unroll
            for (int rr = 0; rr < 4; ++rr) {
                size_t idx = (size_t)(row + rr) * N_ + col;
                yb[idx] = g * acc[i][j][rr] + xb[idx];
            }
        }
}

// ---------------------------------------------------------------------------
// Workspace layout (bytes):
//   q16   @ 0          : 67,108,864
//   qt16  @ 67108864   : 67,108,864
//   att16 @ 134217728  :  8,388,608
//   E     @ 142606336  : 16,777,216      -> total 159,383,552
// Energy partials (4 x 16 MB = 64 MB) live in d_out, which is scratch until
// gemm_bt_out writes y at the end of the stream.
// ---------------------------------------------------------------------------
extern "C" void kernel_launch(void* const* d_in, const int* in_sizes, int n_in,
                              void* d_out, int out_size, void* d_ws, size_t ws_size,
                              hipStream_t stream) {
    const float* x     = (const float*)d_in[0];
    const float* gamma = (const float*)d_in[1];
    float*       y     = (float*)d_out;

    char* ws = (char*)d_ws;
    unsigned short* q16   = (unsigned short*)(ws);
    unsigned short* qt16  = (unsigned short*)(ws + 67108864);
    unsigned short* att16 = (unsigned short*)(ws + 134217728);
    float*          E     = (float*)(ws + 142606336);
    float*          part  = (float*)d_out;   // 4 x 16 MB scratch partials

    convert_transpose<<<dim3(N_ / 64, C_ / 64, B_), dim3(256), 0, stream>>>(x, q16, qt16);
    gemm_energy_upper<<<dim3(10, 4, B_), dim3(256), 0, stream>>>(q16, part);
    mirror_sum<<<dim3(4, 10, B_), dim3(256), 0, stream>>>(part, E);
    softmax_neg<<<dim3(B_ * C_), dim3(256), 0, stream>>>(E, att16);
    gemm_bt_out<<<dim3(N_ / 128, C_ / 128, B_), dim3(256), 0, stream>>>(att16, qt16, x, gamma, y);
}